// Round 10
// baseline (188.857 us; speedup 1.0000x reference)
//
#include <hip/hip_runtime.h>
#include <hip/hip_bf16.h>
#include <float.h>

#define NTOK 8192   // B*G tokens
#define NCB  8192   // codebook entries
#define CDIM 256
#define KPTS 32
#define SQNT 24.0f  // i8 quantization scale
#define INV_CFOLD (SQNT * SQNT * 64.0f)   // d / CFOLD scale, CFOLD = 2/(S^2*128)

typedef __attribute__((ext_vector_type(8))) short short8;   // 8 bf16
typedef __attribute__((ext_vector_type(4))) float f32x4;
typedef __attribute__((ext_vector_type(4))) int i32x4;
typedef unsigned int u32;
typedef unsigned long long u64;

__device__ __forceinline__ void gl_lds16(const void* g, void* l) {
  __builtin_amdgcn_global_load_lds(
      (const __attribute__((address_space(1))) u32*)(g),
      (__attribute__((address_space(3))) u32*)(l), 16, 0, 0);
}

__device__ __forceinline__ ushort bf16_rne(float x) {
  u32 u = __float_as_uint(x);
  return (ushort)((u + 0x7fffu + ((u >> 16) & 1u)) >> 16);
}

__device__ __forceinline__ int pack4i8(int a, int b, int c, int d) {
  return (a & 0xff) | ((b & 0xff) << 8) | ((c & 0xff) << 16) | ((d & 0xff) << 24);
}

// ---------------- fused prep (unchanged from R9) ----------------
__global__ __launch_bounds__(256) void prep_k(
    const float* __restrict__ pf, const float* __restrict__ cb,
    const float* __restrict__ w1, const float* __restrict__ w2,
    const float* __restrict__ w3,
    i32x4* __restrict__ pf1, i32x4* __restrict__ pf2,
    i32x4* __restrict__ cb1, i32x4* __restrict__ cb2,
    ushort* __restrict__ cb_bf, ushort* __restrict__ w1s,
    ushort* __restrict__ w2s, ushort* __restrict__ w3s,
    float* __restrict__ cnorm) {
  __shared__ float cred[4][16];
  int gid = blockIdx.x * 4 + (threadIdx.x >> 6);
  int wv = threadIdx.x >> 6;
  int lane = threadIdx.x & 63, r16 = lane & 15, quad = lane >> 4;
  if (gid < 4096) {
    bool is_cb = gid >= 2048;
    int t = is_cb ? gid - 2048 : gid;
    int tile = t >> 2, kb = t & 3;   // kb64
    const float* src = is_cb ? cb : pf;
    int row = tile * 16 + r16;
    const float* sp = src + (size_t)row * CDIM + kb * 64 + quad * 16;
    float4 v0 = ((const float4*)sp)[0];
    float4 v1 = ((const float4*)sp)[1];
    float4 v2 = ((const float4*)sp)[2];
    float4 v3 = ((const float4*)sp)[3];
    float x[16] = {v0.x, v0.y, v0.z, v0.w, v1.x, v1.y, v1.z, v1.w,
                   v2.x, v2.y, v2.z, v2.w, v3.x, v3.y, v3.z, v3.w};
    int q1[16], q2[16];
    float s = 0.f;
#pragma unroll
    for (int e = 0; e < 16; e++) {
      float as = x[e] * SQNT;
      float a1 = rintf(as);
      a1 = fminf(fmaxf(a1, -127.f), 127.f);
      float a2 = rintf((as - a1) * 128.f);
      a2 = fminf(fmaxf(a2, -127.f), 127.f);
      q1[e] = (int)a1;
      q2[e] = (int)a2;
      s += x[e] * x[e];
    }
    i32x4 p1 = {pack4i8(q1[0], q1[1], q1[2], q1[3]),
                pack4i8(q1[4], q1[5], q1[6], q1[7]),
                pack4i8(q1[8], q1[9], q1[10], q1[11]),
                pack4i8(q1[12], q1[13], q1[14], q1[15])};
    i32x4 p2 = {pack4i8(q2[0], q2[1], q2[2], q2[3]),
                pack4i8(q2[4], q2[5], q2[6], q2[7]),
                pack4i8(q2[8], q2[9], q2[10], q2[11]),
                pack4i8(q2[12], q2[13], q2[14], q2[15])};
    size_t o = (size_t)t * 64 + lane;
    (is_cb ? cb1 : pf1)[o] = p1;
    (is_cb ? cb2 : pf2)[o] = p2;
    if (is_cb) {
      int kb32 = 2 * kb + (quad >> 1);
      int slot0 = ((2 * quad) & 3) * 16 + r16;
      int slot1 = ((2 * quad + 1) & 3) * 16 + r16;
      size_t bo = ((size_t)tile * 8 + kb32) * 512;
      short8 vh0 = {(short)bf16_rne(x[0]), (short)bf16_rne(x[1]),
                    (short)bf16_rne(x[2]), (short)bf16_rne(x[3]),
                    (short)bf16_rne(x[4]), (short)bf16_rne(x[5]),
                    (short)bf16_rne(x[6]), (short)bf16_rne(x[7])};
      short8 vh1 = {(short)bf16_rne(x[8]), (short)bf16_rne(x[9]),
                    (short)bf16_rne(x[10]), (short)bf16_rne(x[11]),
                    (short)bf16_rne(x[12]), (short)bf16_rne(x[13]),
                    (short)bf16_rne(x[14]), (short)bf16_rne(x[15])};
      *(short8*)(cb_bf + bo + (size_t)slot0 * 8) = vh0;
      *(short8*)(cb_bf + bo + (size_t)slot1 * 8) = vh1;
      s += __shfl_xor(s, 16, 64);
      s += __shfl_xor(s, 32, 64);
      if (quad == 0) cred[wv][r16] = s;
      __syncthreads();
      if (threadIdx.x < 16) {
        int ctile = blockIdx.x - 512;
        cnorm[ctile * 16 + threadIdx.x] =
            cred[0][threadIdx.x] + cred[1][threadIdx.x] +
            cred[2][threadIdx.x] + cred[3][threadIdx.x];
      }
    }
  } else if (gid < 4656) {
    int t = gid - 4096;
    const float* src;
    ushort* dst;
    int KB;
    if (t < 256)      { src = w1; dst = w1s; KB = 8; }
    else if (t < 512) { src = w2; dst = w2s; KB = 16; t -= 256; }
    else              { src = w3; dst = w3s; KB = 8;  t -= 512; }
    int tile = t / KB, kb = t - tile * KB, K = KB * 32;
    int row = tile * 16 + r16;
    const float* sp = src + (size_t)row * K + kb * 32 + quad * 8;
    float4 a = ((const float4*)sp)[0];
    float4 b = ((const float4*)sp)[1];
    short8 vh = {(short)bf16_rne(a.x), (short)bf16_rne(a.y),
                 (short)bf16_rne(a.z), (short)bf16_rne(a.w),
                 (short)bf16_rne(b.x), (short)bf16_rne(b.y),
                 (short)bf16_rne(b.z), (short)bf16_rne(b.w)};
    *(short8*)(dst + ((size_t)tile * KB + kb) * 512 + lane * 8) = vh;
  }
}

// -------- i8 MFMA distance GEMM + argmin (R6 exact: best measured 67.7) ----
__global__ __launch_bounds__(256, 2) void argmin_k(
    const char* __restrict__ A1g, const char* __restrict__ A2g,
    const char* __restrict__ B1g, const char* __restrict__ B2g,
    const float* __restrict__ cnorm, u64* __restrict__ pkeys) {
  __shared__ char lds[32 * 1024];
  int tid = threadIdx.x;
  int ns = blockIdx.x, mt = blockIdx.y;
  int wv = tid >> 6, lane = tid & 63;
  int quad = lane >> 4, r16 = lane & 15;
  int wr = wv >> 1, wc = wv & 1;

  int bvi[4][4], bii[4][4];
#pragma unroll
  for (int i = 0; i < 4; i++)
#pragma unroll
    for (int r = 0; r < 4; r++) { bvi[i][r] = 0x7fffffff; bii[i][r] = 0x7fffffff; }

  const char* bsrc = (wv == 0) ? A1g : (wv == 1) ? A2g : (wv == 2) ? B1g : B2g;

  for (int nts = 0; nts < 4; ++nts) {
    int nt = ns * 4 + nts;
    i32x4 am[4][4], ac[4][4];
#pragma unroll
    for (int i = 0; i < 4; i++)
#pragma unroll
      for (int j = 0; j < 4; j++) {
        am[i][j] = (i32x4){0, 0, 0, 0};
        ac[i][j] = (i32x4){0, 0, 0, 0};
      }
    for (int kb = 0; kb < 4; ++kb) {
#pragma unroll
      for (int u = 0; u < 8; ++u) {
        int gt = ((wv < 2) ? mt : nt) * 8 + u;
        gl_lds16(bsrc + ((size_t)gt * 4 + kb) * 1024 + lane * 16,
                 lds + (wv * 8 + u) * 1024);
      }
      __syncthreads();
      i32x4 f1[4], f2[4], g1[4], g2[4];
#pragma unroll
      for (int i = 0; i < 4; i++) {
        f1[i] = *(const i32x4*)(lds + (wr * 4 + i) * 1024 + lane * 16);
        f2[i] = *(const i32x4*)(lds + (8 + wr * 4 + i) * 1024 + lane * 16);
      }
#pragma unroll
      for (int j = 0; j < 4; j++) {
        g1[j] = *(const i32x4*)(lds + (16 + wc * 4 + j) * 1024 + lane * 16);
        g2[j] = *(const i32x4*)(lds + (24 + wc * 4 + j) * 1024 + lane * 16);
      }
#pragma unroll
      for (int i = 0; i < 4; i++)
#pragma unroll
        for (int j = 0; j < 4; j++) {
          am[i][j] = __builtin_amdgcn_mfma_i32_16x16x64_i8(f1[i], g1[j], am[i][j], 0, 0, 0);
          ac[i][j] = __builtin_amdgcn_mfma_i32_16x16x64_i8(f1[i], g2[j], ac[i][j], 0, 0, 0);
          ac[i][j] = __builtin_amdgcn_mfma_i32_16x16x64_i8(f2[i], g1[j], ac[i][j], 0, 0, 0);
        }
      __syncthreads();
    }
#pragma unroll
    for (int j = 0; j < 4; j++) {
      int col = nt * 128 + wc * 64 + j * 16 + r16;
      int cni = __float2int_rn(cnorm[col] * INV_CFOLD);
#pragma unroll
      for (int i = 0; i < 4; i++)
#pragma unroll
        for (int r = 0; r < 4; r++) {
          int di = cni - (am[i][j][r] * 128 + ac[i][j][r]);
          if (di < bvi[i][r]) { bvi[i][r] = di; bii[i][r] = col; }
        }
    }
  }
#pragma unroll
  for (int m = 1; m < 16; m <<= 1) {
#pragma unroll
    for (int i = 0; i < 4; i++)
#pragma unroll
      for (int r = 0; r < 4; r++) {
        int ov = __shfl_xor(bvi[i][r], m, 64);
        int oi = __shfl_xor(bii[i][r], m, 64);
        if (ov < bvi[i][r] || (ov == bvi[i][r] && oi < bii[i][r])) {
          bvi[i][r] = ov;
          bii[i][r] = oi;
        }
      }
  }
  if (r16 == 0) {
#pragma unroll
    for (int i = 0; i < 4; i++)
#pragma unroll
      for (int r = 0; r < 4; r++) {
        int row = mt * 128 + wr * 64 + i * 16 + quad * 4 + r;
        u32 mk = (u32)(bvi[i][r] + (1 << 30));
        pkeys[(size_t)(ns * 2 + wc) * NTOK + row] = ((u64)mk << 32) | (u32)bii[i][r];
      }
  }
}

// ---- merge 32 candidate slots + gather bf16 codebook fragments ----
__global__ __launch_bounds__(256) void gather_k(const u64* __restrict__ pkeys,
                                                const ushort* __restrict__ cb_bf,
                                                ushort* __restrict__ quant) {
  int gid = blockIdx.x * 4 + (threadIdx.x >> 6);
  int lane = threadIdx.x & 63, r16 = lane & 15, quad = lane >> 4;
  int tile = gid >> 3, kb = gid & 7;
  int row = tile * 16 + r16;
  u64 best = pkeys[row];
#pragma unroll
  for (int s = 1; s < 32; s++) {
    u64 v = pkeys[(size_t)s * NTOK + row];
    if (v < best) best = v;
  }
  int id = (int)(u32)best;
  short8 v = *(const short8*)(cb_bf + ((size_t)(id >> 4) * 8 + kb) * 512 +
                              (size_t)((id & 15) + quad * 16) * 8);
  *(short8*)(quant + ((size_t)tile * 8 + kb) * 512 + lane * 8) = v;
}

// -------- gemm1: weight-stationary 128x64, h1 = relu(quant*w1^T+b1) --------
__global__ __launch_bounds__(256, 3) void gemm1_k(
    const ushort* __restrict__ quant, const ushort* __restrict__ w1s,
    const float* __restrict__ b1, ushort* __restrict__ h1) {
  __shared__ ushort Bs[32 * 512];     // 4 jt x 8 kb, staged once
  __shared__ ushort As[2][8 * 512];   // 8 row-tiles, double-buffered per kb
  int tid = threadIdx.x;
  int nt = blockIdx.x, mt = blockIdx.y;
  int wv = tid >> 6, lane = tid & 63;
  int quad = lane >> 4, r16 = lane & 15;

#pragma unroll
  for (int u = 0; u < 8; ++u) {
    int c = wv + u * 4;
    int jt = nt * 4 + (c >> 3), kb = c & 7;
    gl_lds16(w1s + ((size_t)jt * 8 + kb) * 512 + lane * 8, Bs + (size_t)c * 512);
  }
#pragma unroll
  for (int v = 0; v < 2; ++v) {
    int c = wv * 2 + v;
    gl_lds16(quant + ((size_t)(mt * 8 + c) * 8 + 0) * 512 + lane * 8,
             As[0] + (size_t)c * 512);
  }
  __syncthreads();

  f32x4 acc[2][4];
#pragma unroll
  for (int i = 0; i < 2; i++)
#pragma unroll
    for (int j = 0; j < 4; j++) acc[i][j] = (f32x4){0.f, 0.f, 0.f, 0.f};

  for (int kb = 0; kb < 8; ++kb) {
    if (kb < 7) {
#pragma unroll
      for (int v = 0; v < 2; ++v) {
        int c = wv * 2 + v;
        gl_lds16(quant + ((size_t)(mt * 8 + c) * 8 + kb + 1) * 512 + lane * 8,
                 As[(kb + 1) & 1] + (size_t)c * 512);
      }
    }
    const ushort* A = As[kb & 1];
    short8 fa[2], fb[4];
#pragma unroll
    for (int i = 0; i < 2; i++)
      fa[i] = *(const short8*)(A + (size_t)(wv * 2 + i) * 512 + lane * 8);
#pragma unroll
    for (int j = 0; j < 4; j++)
      fb[j] = *(const short8*)(Bs + (size_t)(j * 8 + kb) * 512 + lane * 8);
#pragma unroll
    for (int i = 0; i < 2; i++)
#pragma unroll
      for (int j = 0; j < 4; j++)
        acc[i][j] = __builtin_amdgcn_mfma_f32_16x16x32_bf16(fa[i], fb[j], acc[i][j], 0, 0, 0);
    __syncthreads();
  }

#pragma unroll
  for (int j = 0; j < 4; j++) {
    int col = nt * 64 + j * 16 + r16;
    float bj = b1[col];
#pragma unroll
    for (int i = 0; i < 2; i++) {
#pragma unroll
      for (int reg = 0; reg < 4; reg++) {
        int row = mt * 128 + (wv * 2 + i) * 16 + quad * 4 + reg;
        float v = fmaxf(acc[i][j][reg] + bj, 0.f);
        size_t o = ((size_t)(row >> 4) * 16 + (col >> 5)) * 512 +
                   (size_t)(((col >> 3) & 3) * 16 + (row & 15)) * 8 + (col & 7);
        h1[o] = bf16_rne(v);
      }
    }
  }
}

// -------- gemm2: weight-stationary 128x32, h2 = relu(h1*w2^T+b2) --------
__global__ __launch_bounds__(256, 3) void gemm2_k(
    const ushort* __restrict__ h1, const ushort* __restrict__ w2s,
    const float* __restrict__ b2, ushort* __restrict__ h2) {
  __shared__ ushort Bs[32 * 512];     // 2 jt x 16 kb
  __shared__ ushort As[2][8 * 512];
  int tid = threadIdx.x;
  int nt = blockIdx.x, mt = blockIdx.y;
  int wv = tid >> 6, lane = tid & 63;
  int quad = lane >> 4, r16 = lane & 15;

#pragma unroll
  for (int u = 0; u < 8; ++u) {
    int c = wv + u * 4;
    int jt = nt * 2 + (c >> 4), kb = c & 15;
    gl_lds16(w2s + ((size_t)jt * 16 + kb) * 512 + lane * 8, Bs + (size_t)c * 512);
  }
#pragma unroll
  for (int v = 0; v < 2; ++v) {
    int c = wv * 2 + v;
    gl_lds16(h1 + ((size_t)(mt * 8 + c) * 16 + 0) * 512 + lane * 8,
             As[0] + (size_t)c * 512);
  }
  __syncthreads();

  f32x4 acc[2][2];
#pragma unroll
  for (int i = 0; i < 2; i++)
#pragma unroll
    for (int j = 0; j < 2; j++) acc[i][j] = (f32x4){0.f, 0.f, 0.f, 0.f};

  for (int kb = 0; kb < 16; ++kb) {
    if (kb < 15) {
#pragma unroll
      for (int v = 0; v < 2; ++v) {
        int c = wv * 2 + v;
        gl_lds16(h1 + ((size_t)(mt * 8 + c) * 16 + kb + 1) * 512 + lane * 8,
                 As[(kb + 1) & 1] + (size_t)c * 512);
      }
    }
    const ushort* A = As[kb & 1];
    short8 fa[2], fb[2];
#pragma unroll
    for (int i = 0; i < 2; i++)
      fa[i] = *(const short8*)(A + (size_t)(wv * 2 + i) * 512 + lane * 8);
#pragma unroll
    for (int j = 0; j < 2; j++)
      fb[j] = *(const short8*)(Bs + (size_t)(j * 16 + kb) * 512 + lane * 8);
#pragma unroll
    for (int i = 0; i < 2; i++)
#pragma unroll
      for (int j = 0; j < 2; j++)
        acc[i][j] = __builtin_amdgcn_mfma_f32_16x16x32_bf16(fa[i], fb[j], acc[i][j], 0, 0, 0);
    __syncthreads();
  }

#pragma unroll
  for (int j = 0; j < 2; j++) {
    int col = nt * 32 + j * 16 + r16;
    float bj = b2[col];
#pragma unroll
    for (int i = 0; i < 2; i++) {
#pragma unroll
      for (int reg = 0; reg < 4; reg++) {
        int row = mt * 128 + (wv * 2 + i) * 16 + quad * 4 + reg;
        float v = fmaxf(acc[i][j][reg] + bj, 0.f);
        size_t o = ((size_t)(row >> 4) * 8 + (col >> 5)) * 512 +
                   (size_t)(((col >> 3) & 3) * 16 + (row & 15)) * 8 + (col & 7);
        h2[o] = bf16_rne(v);
      }
    }
  }
}

// -------- gemm3 (32 tokens x 96) + chamfer, weights + A staged once --------
// Dynamic LDS: Bs [0,48K) 6jtx8kb; As [48K,64K) 2 tiles x 8kb;
//              rec [64K,76K); gts [76K,88K); wsum tail.
__global__ __launch_bounds__(256) void gemm3_chamfer_k(
    const ushort* __restrict__ h2, const ushort* __restrict__ w3s,
    const float* __restrict__ b3, const float* __restrict__ neigh,
    float* __restrict__ out) {
  extern __shared__ char lds[];
  ushort* Bs = (ushort*)lds;
  ushort* As = (ushort*)(lds + 49152);
  float* recp = (float*)(lds + 65536);
  float* gtsp = (float*)(lds + 77824);
  float* wsum = (float*)(lds + 90112);
  int tid = threadIdx.x;
  int mt = blockIdx.x;   // 32-token group
  int wv = tid >> 6, lane = tid & 63;
  int quad = lane >> 4, r16 = lane & 15;

#pragma unroll
  for (int u = 0; u < 12; ++u) {
    int c = wv + u * 4;
    gl_lds16(w3s + (size_t)c * 512 + lane * 8, Bs + (size_t)c * 512);
  }
#pragma unroll
  for (int v = 0; v < 4; ++v) {
    int c = wv * 4 + v;
    gl_lds16(h2 + ((size_t)(mt * 2 + (c >> 3)) * 8 + (c & 7)) * 512 + lane * 8,
             As + (size_t)c * 512);
  }
  // stage ground truth (plain stores, covered by the same barrier)
#pragma unroll
  for (int s = 0; s < 3; s++) {
    int idx = tid + s * 256;
    int t = idx / 24, c = (idx - t * 24) * 4;
    *(float4*)(gtsp + (size_t)t * 96 + c) =
        *(const float4*)(neigh + (size_t)(mt * 32 + t) * 96 + c);
  }
  __syncthreads();

  // 12 (i,j) pairs over 4 waves, 3 each
#pragma unroll
  for (int w = 0; w < 3; ++w) {
    int p = wv + w * 4;
    int i = p / 6, j = p - i * 6;
    f32x4 acc = (f32x4){0.f, 0.f, 0.f, 0.f};
#pragma unroll
    for (int kb = 0; kb < 8; kb++) {
      short8 fa = *(const short8*)(As + (size_t)(i * 8 + kb) * 512 + lane * 8);
      short8 fb = *(const short8*)(Bs + (size_t)(j * 8 + kb) * 512 + lane * 8);
      acc = __builtin_amdgcn_mfma_f32_16x16x32_bf16(fa, fb, acc, 0, 0, 0);
    }
    int col = j * 16 + r16;
    float bj = b3[col];
#pragma unroll
    for (int reg = 0; reg < 4; reg++) {
      int row_l = i * 16 + quad * 4 + reg;
      recp[(size_t)row_l * 96 + col] = acc[reg] + bj;
    }
  }
  __syncthreads();

  // chamfer: 1024 point-slots, 4 per thread
  float local = 0.f;
#pragma unroll
  for (int pp = 0; pp < 4; ++pp) {
    int p = tid + pp * 256;
    int t = p >> 5, i = p & 31;
    float rx = recp[t * 96 + 3 * i], ry = recp[t * 96 + 3 * i + 1], rz = recp[t * 96 + 3 * i + 2];
    float gx = gtsp[t * 96 + 3 * i], gy = gtsp[t * 96 + 3 * i + 1], gz = gtsp[t * 96 + 3 * i + 2];
    float mA = FLT_MAX, mB = FLT_MAX;
#pragma unroll
    for (int j = 0; j < 32; j++) {
      float dx = rx - gtsp[t * 96 + 3 * j], dy = ry - gtsp[t * 96 + 3 * j + 1],
            dz = rz - gtsp[t * 96 + 3 * j + 2];
      float d = dx * dx + dy * dy + dz * dz;
      mA = fminf(mA, d);
      dx = recp[t * 96 + 3 * j] - gx; dy = recp[t * 96 + 3 * j + 1] - gy;
      dz = recp[t * 96 + 3 * j + 2] - gz;
      d = dx * dx + dy * dy + dz * dz;
      mB = fminf(mB, d);
    }
    local += mA + mB;
  }
#pragma unroll
  for (int off = 32; off; off >>= 1) local += __shfl_down(local, off, 64);
  if (lane == 0) wsum[wv] = local;
  __syncthreads();
  if (tid == 0) {
    float s = wsum[0] + wsum[1] + wsum[2] + wsum[3];
    atomicAdd(out, s * (1.0f / (float)(NTOK * KPTS)));
  }
}

extern "C" void kernel_launch(void* const* d_in, const int* in_sizes, int n_in,
                              void* d_out, int out_size, void* d_ws, size_t ws_size,
                              hipStream_t stream) {
  const float* pf    = (const float*)d_in[0];
  const float* neigh = (const float*)d_in[1];
  const float* cb    = (const float*)d_in[2];
  const float* w1    = (const float*)d_in[3];
  const float* b1    = (const float*)d_in[4];
  const float* w2    = (const float*)d_in[5];
  const float* b2    = (const float*)d_in[6];
  const float* w3    = (const float*)d_in[7];
  const float* b3    = (const float*)d_in[8];
  float* out = (float*)d_out;
  char* base = (char*)d_ws;

  u64*   pkeys = (u64*)base;                       // 2 MB
  float* cnorm = (float*)(base + 0x200000);        // 32 KB
  char*  pf1   = base + 0x210000;                  // 2 MB each
  char*  pf2   = base + 0x410000;
  char*  cb1   = base + 0x610000;
  char*  cb2   = base + 0x810000;
  ushort* cb_bf = (ushort*)(base + 0xA10000);      // 4 MB
  ushort* w1s   = (ushort*)(base + 0xE10000);      // 256 KB
  ushort* w2s   = (ushort*)(base + 0xE50000);      // 256 KB
  ushort* w3s   = (ushort*)(base + 0xE90000);      // 48 KB
  // aliases (producer ordering makes these safe):
  ushort* quant = (ushort*)(base + 0x210000);      // over pf1/pf2 (dead after argmin)
  ushort* h1    = (ushort*)(base + 0x610000);      // over cb1/cb2/cb_bf (dead after gather)
  ushort* h2    = (ushort*)(base + 0xF00000);      // fresh 4 MB

  hipMemsetAsync(d_out, 0, sizeof(float), stream);
  prep_k<<<1164, 256, 0, stream>>>(pf, cb, w1, w2, w3,
                                   (i32x4*)pf1, (i32x4*)pf2, (i32x4*)cb1,
                                   (i32x4*)cb2, cb_bf, w1s, w2s, w3s, cnorm);
  argmin_k<<<dim3(16, 64), 256, 0, stream>>>(pf1, pf2, cb1, cb2, cnorm, pkeys);
  gather_k<<<1024, 256, 0, stream>>>(pkeys, cb_bf, quant);
  gemm1_k<<<dim3(8, 64), 256, 0, stream>>>(quant, w1s, b1, h1);
  gemm2_k<<<dim3(8, 64), 256, 0, stream>>>(h1, w2s, b2, h2);
  gemm3_chamfer_k<<<256, 256, 90128, stream>>>(h2, w3s, b3, neigh, out);
}

// Round 11
// 157.700 us; speedup vs baseline: 1.1976x; 1.1976x over previous
//
#include <hip/hip_runtime.h>
#include <hip/hip_bf16.h>
#include <float.h>

#define NTOK 8192   // B*G tokens
#define NCB  8192   // codebook entries
#define CDIM 256
#define KPTS 32
#define SQNT 24.0f  // i8 quantization scale
#define INV_CFOLD (SQNT * SQNT * 64.0f)   // d / CFOLD scale, CFOLD = 2/(S^2*128)

typedef __attribute__((ext_vector_type(8))) short short8;   // 8 bf16
typedef __attribute__((ext_vector_type(4))) float f32x4;
typedef __attribute__((ext_vector_type(4))) int i32x4;
typedef unsigned int u32;
typedef unsigned long long u64;

__device__ __forceinline__ void gl_lds16(const void* g, void* l) {
  __builtin_amdgcn_global_load_lds(
      (const __attribute__((address_space(1))) u32*)(g),
      (__attribute__((address_space(3))) u32*)(l), 16, 0, 0);
}

__device__ __forceinline__ ushort bf16_rne(float x) {
  u32 u = __float_as_uint(x);
  return (ushort)((u + 0x7fffu + ((u >> 16) & 1u)) >> 16);
}

__device__ __forceinline__ int pack4i8(int a, int b, int c, int d) {
  return (a & 0xff) | ((b & 0xff) << 8) | ((c & 0xff) << 16) | ((d & 0xff) << 24);
}

// ---------------- fused prep (R9) + out zeroing ----------------
__global__ __launch_bounds__(256) void prep_k(
    const float* __restrict__ pf, const float* __restrict__ cb,
    const float* __restrict__ w1, const float* __restrict__ w2,
    const float* __restrict__ w3,
    i32x4* __restrict__ pf1, i32x4* __restrict__ pf2,
    i32x4* __restrict__ cb1, i32x4* __restrict__ cb2,
    ushort* __restrict__ cb_bf, ushort* __restrict__ w1s,
    ushort* __restrict__ w2s, ushort* __restrict__ w3s,
    float* __restrict__ cnorm, float* __restrict__ out) {
  __shared__ float cred[4][16];
  if (blockIdx.x == 0 && threadIdx.x == 0) out[0] = 0.f;
  int gid = blockIdx.x * 4 + (threadIdx.x >> 6);
  int wv = threadIdx.x >> 6;
  int lane = threadIdx.x & 63, r16 = lane & 15, quad = lane >> 4;
  if (gid < 4096) {
    bool is_cb = gid >= 2048;
    int t = is_cb ? gid - 2048 : gid;
    int tile = t >> 2, kb = t & 3;   // kb64
    const float* src = is_cb ? cb : pf;
    int row = tile * 16 + r16;
    const float* sp = src + (size_t)row * CDIM + kb * 64 + quad * 16;
    float4 v0 = ((const float4*)sp)[0];
    float4 v1 = ((const float4*)sp)[1];
    float4 v2 = ((const float4*)sp)[2];
    float4 v3 = ((const float4*)sp)[3];
    float x[16] = {v0.x, v0.y, v0.z, v0.w, v1.x, v1.y, v1.z, v1.w,
                   v2.x, v2.y, v2.z, v2.w, v3.x, v3.y, v3.z, v3.w};
    int q1[16], q2[16];
    float s = 0.f;
#pragma unroll
    for (int e = 0; e < 16; e++) {
      float as = x[e] * SQNT;
      float a1 = rintf(as);
      a1 = fminf(fmaxf(a1, -127.f), 127.f);
      float a2 = rintf((as - a1) * 128.f);
      a2 = fminf(fmaxf(a2, -127.f), 127.f);
      q1[e] = (int)a1;
      q2[e] = (int)a2;
      s += x[e] * x[e];
    }
    i32x4 p1 = {pack4i8(q1[0], q1[1], q1[2], q1[3]),
                pack4i8(q1[4], q1[5], q1[6], q1[7]),
                pack4i8(q1[8], q1[9], q1[10], q1[11]),
                pack4i8(q1[12], q1[13], q1[14], q1[15])};
    i32x4 p2 = {pack4i8(q2[0], q2[1], q2[2], q2[3]),
                pack4i8(q2[4], q2[5], q2[6], q2[7]),
                pack4i8(q2[8], q2[9], q2[10], q2[11]),
                pack4i8(q2[12], q2[13], q2[14], q2[15])};
    size_t o = (size_t)t * 64 + lane;
    (is_cb ? cb1 : pf1)[o] = p1;
    (is_cb ? cb2 : pf2)[o] = p2;
    if (is_cb) {
      int kb32 = 2 * kb + (quad >> 1);
      int slot0 = ((2 * quad) & 3) * 16 + r16;
      int slot1 = ((2 * quad + 1) & 3) * 16 + r16;
      size_t bo = ((size_t)tile * 8 + kb32) * 512;
      short8 vh0 = {(short)bf16_rne(x[0]), (short)bf16_rne(x[1]),
                    (short)bf16_rne(x[2]), (short)bf16_rne(x[3]),
                    (short)bf16_rne(x[4]), (short)bf16_rne(x[5]),
                    (short)bf16_rne(x[6]), (short)bf16_rne(x[7])};
      short8 vh1 = {(short)bf16_rne(x[8]), (short)bf16_rne(x[9]),
                    (short)bf16_rne(x[10]), (short)bf16_rne(x[11]),
                    (short)bf16_rne(x[12]), (short)bf16_rne(x[13]),
                    (short)bf16_rne(x[14]), (short)bf16_rne(x[15])};
      *(short8*)(cb_bf + bo + (size_t)slot0 * 8) = vh0;
      *(short8*)(cb_bf + bo + (size_t)slot1 * 8) = vh1;
      s += __shfl_xor(s, 16, 64);
      s += __shfl_xor(s, 32, 64);
      if (quad == 0) cred[wv][r16] = s;
      __syncthreads();
      if (threadIdx.x < 16) {
        int ctile = blockIdx.x - 512;
        cnorm[ctile * 16 + threadIdx.x] =
            cred[0][threadIdx.x] + cred[1][threadIdx.x] +
            cred[2][threadIdx.x] + cred[3][threadIdx.x];
      }
    }
  } else if (gid < 4656) {
    int t = gid - 4096;
    const float* src;
    ushort* dst;
    int KB;
    if (t < 256)      { src = w1; dst = w1s; KB = 8; }
    else if (t < 512) { src = w2; dst = w2s; KB = 16; t -= 256; }
    else              { src = w3; dst = w3s; KB = 8;  t -= 512; }
    int tile = t / KB, kb = t - tile * KB, K = KB * 32;
    int row = tile * 16 + r16;
    const float* sp = src + (size_t)row * K + kb * 32 + quad * 8;
    float4 a = ((const float4*)sp)[0];
    float4 b = ((const float4*)sp)[1];
    short8 vh = {(short)bf16_rne(a.x), (short)bf16_rne(a.y),
                 (short)bf16_rne(a.z), (short)bf16_rne(a.w),
                 (short)bf16_rne(b.x), (short)bf16_rne(b.y),
                 (short)bf16_rne(b.z), (short)bf16_rne(b.w)};
    *(short8*)(dst + ((size_t)tile * KB + kb) * 512 + lane * 8) = vh;
  }
}

// -------- i8 MFMA distance GEMM + argmin, A-persistent LDS --------
// A (128 rows, both levels) staged ONCE into 64 KB; per-(nts,kb) stage only
// B (16 KB). Staged bytes/block: 512 KB -> 320 KB. Dynamic LDS = 80 KB
// exactly -> 2 blocks/CU.
__global__ __launch_bounds__(256, 2) void argmin_k(
    const char* __restrict__ A1g, const char* __restrict__ A2g,
    const char* __restrict__ B1g, const char* __restrict__ B2g,
    const float* __restrict__ cnorm, u64* __restrict__ pkeys) {
  extern __shared__ char lds[];
  char* A1 = lds;               // 32 KB: [tile(8)][kb(4)] x 1KB
  char* A2 = lds + 32768;       // 32 KB
  char* Bb = lds + 65536;       // 16 KB: B1 8x1KB | B2 8x1KB
  int tid = threadIdx.x;
  int ns = blockIdx.x, mt = blockIdx.y;
  int wv = tid >> 6, lane = tid & 63;
  int quad = lane >> 4, r16 = lane & 15;
  int wr = wv >> 1, wc = wv & 1;

  int bvi[4][4], bii[4][4];
#pragma unroll
  for (int i = 0; i < 4; i++)
#pragma unroll
    for (int r = 0; r < 4; r++) { bvi[i][r] = 0x7fffffff; bii[i][r] = 0x7fffffff; }

  // ---- stage A once: 64 chunks of 1 KB, 16 per wave ----
#pragma unroll
  for (int u = 0; u < 16; ++u) {
    int c = wv + u * 4;          // 0..63
    const char* src = (c < 32) ? A1g : A2g;
    char* dst = (c < 32) ? A1 : A2;
    int cc = c & 31;             // tile*4 + kb
    gl_lds16(src + ((size_t)(mt * 8 + (cc >> 2)) * 4 + (cc & 3)) * 1024 + lane * 16,
             dst + cc * 1024);
  }

  i32x4 am[4][4], ac[4][4];
  for (int s = 0; s < 16; ++s) {
    int nts = s >> 2, kb = s & 3;
    int nt = ns * 4 + nts;
    // stage B: 16 chunks, 4 per wave
#pragma unroll
    for (int u = 0; u < 4; ++u) {
      int c = wv * 4 + u;
      const char* src = (c < 8) ? B1g : B2g;
      int gt = nt * 8 + (c & 7);
      gl_lds16(src + ((size_t)gt * 4 + kb) * 1024 + lane * 16, Bb + c * 1024);
    }
    __syncthreads();   // A (first iter) + B ready
    if (kb == 0) {
#pragma unroll
      for (int i = 0; i < 4; i++)
#pragma unroll
        for (int j = 0; j < 4; j++) {
          am[i][j] = (i32x4){0, 0, 0, 0};
          ac[i][j] = (i32x4){0, 0, 0, 0};
        }
    }
    i32x4 f1[4], f2[4], g1[4], g2[4];
#pragma unroll
    for (int i = 0; i < 4; i++) {
      f1[i] = *(const i32x4*)(A1 + ((wr * 4 + i) * 4 + kb) * 1024 + lane * 16);
      f2[i] = *(const i32x4*)(A2 + ((wr * 4 + i) * 4 + kb) * 1024 + lane * 16);
    }
#pragma unroll
    for (int j = 0; j < 4; j++) {
      g1[j] = *(const i32x4*)(Bb + (wc * 4 + j) * 1024 + lane * 16);
      g2[j] = *(const i32x4*)(Bb + (8 + wc * 4 + j) * 1024 + lane * 16);
    }
#pragma unroll
    for (int i = 0; i < 4; i++)
#pragma unroll
      for (int j = 0; j < 4; j++) {
        am[i][j] = __builtin_amdgcn_mfma_i32_16x16x64_i8(f1[i], g1[j], am[i][j], 0, 0, 0);
        ac[i][j] = __builtin_amdgcn_mfma_i32_16x16x64_i8(f1[i], g2[j], ac[i][j], 0, 0, 0);
        ac[i][j] = __builtin_amdgcn_mfma_i32_16x16x64_i8(f2[i], g1[j], ac[i][j], 0, 0, 0);
      }
    if (kb == 3) {
      // integer fold: di = cni - (am*128 + ac); strict < keeps first index
#pragma unroll
      for (int j = 0; j < 4; j++) {
        int col = nt * 128 + wc * 64 + j * 16 + r16;
        int cni = __float2int_rn(cnorm[col] * INV_CFOLD);
#pragma unroll
        for (int i = 0; i < 4; i++)
#pragma unroll
          for (int r = 0; r < 4; r++) {
            int di = cni - (am[i][j][r] * 128 + ac[i][j][r]);
            if (di < bvi[i][r]) { bvi[i][r] = di; bii[i][r] = col; }
          }
      }
    }
    __syncthreads();   // guard B overwrite
  }
#pragma unroll
  for (int m = 1; m < 16; m <<= 1) {
#pragma unroll
    for (int i = 0; i < 4; i++)
#pragma unroll
      for (int r = 0; r < 4; r++) {
        int ov = __shfl_xor(bvi[i][r], m, 64);
        int oi = __shfl_xor(bii[i][r], m, 64);
        if (ov < bvi[i][r] || (ov == bvi[i][r] && oi < bii[i][r])) {
          bvi[i][r] = ov;
          bii[i][r] = oi;
        }
      }
  }
  if (r16 == 0) {
#pragma unroll
    for (int i = 0; i < 4; i++)
#pragma unroll
      for (int r = 0; r < 4; r++) {
        int row = mt * 128 + wr * 64 + i * 16 + quad * 4 + r;
        u32 mk = (u32)(bvi[i][r] + (1 << 30));
        pkeys[(size_t)(ns * 2 + wc) * NTOK + row] = ((u64)mk << 32) | (u32)bii[i][r];
      }
  }
}

// -------- fused MLP (R8 exact): 16 tokens/block, 512 blocks x 512 thr ----
__global__ __launch_bounds__(512) void mlp_fused_k(
    const u64* __restrict__ pkeys, const ushort* __restrict__ cb_bf,
    const ushort* __restrict__ w1s, const float* __restrict__ b1,
    const ushort* __restrict__ w2s, const float* __restrict__ b2,
    const ushort* __restrict__ w3s, const float* __restrict__ b3,
    const float* __restrict__ neigh, float* __restrict__ out) {
  __shared__ ushort qs_h2[8 * 512];
  __shared__ ushort h1s[16 * 512];
  __shared__ float rec[16 * 96];
  __shared__ float gts[16 * 96];
  __shared__ int ids[16];
  __shared__ float wsum[8];

  int tid = threadIdx.x;
  int t0 = blockIdx.x * 16;
  int wv = tid >> 6, lane = tid & 63;
  int quad = lane >> 4, r16 = lane & 15;

  {
    int row_l = tid >> 5, sl = tid & 31;
    u64 best = pkeys[(size_t)sl * NTOK + t0 + row_l];
#pragma unroll
    for (int m = 1; m < 32; m <<= 1) {
      u64 o = __shfl_xor((unsigned long long)best, m, 64);
      if (o < best) best = o;
    }
    if (sl == 0) ids[row_l] = (int)(u32)best;
  }
  __syncthreads();

  {
    int kb = wv;
    int id = ids[r16];
    short8 v = *(const short8*)(cb_bf + ((size_t)(id >> 4) * 8 + kb) * 512 +
                                (size_t)((id & 15) + quad * 16) * 8);
    *(short8*)(qs_h2 + (size_t)kb * 512 + lane * 8) = v;
  }
  __syncthreads();

  short8 fa1[8];
#pragma unroll
  for (int kb = 0; kb < 8; kb++)
    fa1[kb] = *(const short8*)(qs_h2 + (size_t)kb * 512 + lane * 8);
  __syncthreads();

#pragma unroll
  for (int jj = 0; jj < 4; ++jj) {
    int jt = wv + jj * 8;
    f32x4 acc = (f32x4){0.f, 0.f, 0.f, 0.f};
#pragma unroll
    for (int kb = 0; kb < 8; kb++) {
      short8 fb = *(const short8*)(w1s + ((size_t)jt * 8 + kb) * 512 + lane * 8);
      acc = __builtin_amdgcn_mfma_f32_16x16x32_bf16(fa1[kb], fb, acc, 0, 0, 0);
    }
    int col = jt * 16 + r16;
    float bj = b1[col];
#pragma unroll
    for (int reg = 0; reg < 4; reg++) {
      int row_l = quad * 4 + reg;
      float v = fmaxf(acc[reg] + bj, 0.f);
      size_t o = (size_t)(col >> 5) * 512 +
                 (size_t)(((col >> 3) & 3) * 16 + row_l) * 8 + (col & 7);
      h1s[o] = bf16_rne(v);
    }
  }
  __syncthreads();

#pragma unroll
  for (int jj = 0; jj < 2; ++jj) {
    int jt = wv + jj * 8;
    f32x4 acc = (f32x4){0.f, 0.f, 0.f, 0.f};
#pragma unroll
    for (int kb = 0; kb < 16; kb++) {
      short8 fa = *(const short8*)(h1s + (size_t)kb * 512 + lane * 8);
      short8 fb = *(const short8*)(w2s + ((size_t)jt * 16 + kb) * 512 + lane * 8);
      acc = __builtin_amdgcn_mfma_f32_16x16x32_bf16(fa, fb, acc, 0, 0, 0);
    }
    int col = jt * 16 + r16;
    float bj = b2[col];
#pragma unroll
    for (int reg = 0; reg < 4; reg++) {
      int row_l = quad * 4 + reg;
      float v = fmaxf(acc[reg] + bj, 0.f);
      size_t o = (size_t)(col >> 5) * 512 +
                 (size_t)(((col >> 3) & 3) * 16 + row_l) * 8 + (col & 7);
      qs_h2[o] = bf16_rne(v);
    }
  }
  __syncthreads();

  if (tid < 384) {
    int t = tid / 24, c = (tid - t * 24) * 4;
    *(float4*)(gts + (size_t)t * 96 + c) =
        *(const float4*)(neigh + (size_t)(t0 + t) * 96 + c);
  }

  if (wv < 6) {
    int jt = wv;
    f32x4 acc = (f32x4){0.f, 0.f, 0.f, 0.f};
#pragma unroll
    for (int kb = 0; kb < 8; kb++) {
      short8 fa = *(const short8*)(qs_h2 + (size_t)kb * 512 + lane * 8);
      short8 fb = *(const short8*)(w3s + ((size_t)jt * 8 + kb) * 512 + lane * 8);
      acc = __builtin_amdgcn_mfma_f32_16x16x32_bf16(fa, fb, acc, 0, 0, 0);
    }
    int col = jt * 16 + r16;
    float bj = b3[col];
#pragma unroll
    for (int reg = 0; reg < 4; reg++) {
      int row_l = quad * 4 + reg;
      rec[(size_t)row_l * 96 + col] = acc[reg] + bj;
    }
  }
  __syncthreads();

  float local = 0.f;
  {
    int t = tid >> 5, i = tid & 31;
    float rx = rec[t * 96 + 3 * i], ry = rec[t * 96 + 3 * i + 1], rz = rec[t * 96 + 3 * i + 2];
    float gx = gts[t * 96 + 3 * i], gy = gts[t * 96 + 3 * i + 1], gz = gts[t * 96 + 3 * i + 2];
    float mA = FLT_MAX, mB = FLT_MAX;
#pragma unroll
    for (int j = 0; j < 32; j++) {
      float dx = rx - gts[t * 96 + 3 * j], dy = ry - gts[t * 96 + 3 * j + 1],
            dz = rz - gts[t * 96 + 3 * j + 2];
      float d = dx * dx + dy * dy + dz * dz;
      mA = fminf(mA, d);
      dx = rec[t * 96 + 3 * j] - gx; dy = rec[t * 96 + 3 * j + 1] - gy;
      dz = rec[t * 96 + 3 * j + 2] - gz;
      d = dx * dx + dy * dy + dz * dz;
      mB = fminf(mB, d);
    }
    local = mA + mB;
  }
#pragma unroll
  for (int off = 32; off; off >>= 1) local += __shfl_down(local, off, 64);
  if (lane == 0) wsum[wv] = local;
  __syncthreads();
  if (tid == 0) {
    float s = 0.f;
#pragma unroll
    for (int w = 0; w < 8; w++) s += wsum[w];
    atomicAdd(out, s * (1.0f / (float)(NTOK * KPTS)));
  }
}

extern "C" void kernel_launch(void* const* d_in, const int* in_sizes, int n_in,
                              void* d_out, int out_size, void* d_ws, size_t ws_size,
                              hipStream_t stream) {
  const float* pf    = (const float*)d_in[0];
  const float* neigh = (const float*)d_in[1];
  const float* cb    = (const float*)d_in[2];
  const float* w1    = (const float*)d_in[3];
  const float* b1    = (const float*)d_in[4];
  const float* w2    = (const float*)d_in[5];
  const float* b2    = (const float*)d_in[6];
  const float* w3    = (const float*)d_in[7];
  const float* b3    = (const float*)d_in[8];
  float* out = (float*)d_out;
  char* base = (char*)d_ws;

  u64*   pkeys = (u64*)base;                       // 2 MB
  float* cnorm = (float*)(base + 0x200000);        // 32 KB
  char*  pf1   = base + 0x210000;                  // 2 MB each
  char*  pf2   = base + 0x410000;
  char*  cb1   = base + 0x610000;
  char*  cb2   = base + 0x810000;
  ushort* cb_bf = (ushort*)(base + 0xA10000);      // 4 MB
  ushort* w1s   = (ushort*)(base + 0xE10000);      // 256 KB
  ushort* w2s   = (ushort*)(base + 0xE50000);      // 256 KB
  ushort* w3s   = (ushort*)(base + 0xE90000);      // 48 KB

  prep_k<<<1164, 256, 0, stream>>>(pf, cb, w1, w2, w3,
                                   (i32x4*)pf1, (i32x4*)pf2, (i32x4*)cb1,
                                   (i32x4*)cb2, cb_bf, w1s, w2s, w3s, cnorm, out);
  argmin_k<<<dim3(16, 64), 256, 81920, stream>>>(pf1, pf2, cb1, cb2, cnorm, pkeys);
  mlp_fused_k<<<512, 512, 0, stream>>>(pkeys, cb_bf, w1s, b1, w2s, b2,
                                       w3s, b3, neigh, out);
}